// Round 7
// baseline (227.827 us; speedup 1.0000x reference)
//
#include <hip/hip_runtime.h>
#include <math.h>

#define N_NODES 100000
#define N_EDGES 1600000
#define F_IN 256
#define HIDDEN 64
#define NEG_SLOPE 0.2f

#define BSHIFT 7               // bucket = dst>>7 (128 nodes/bucket)
#define BMASK 127
#define W_BUCKETS 782          // ceil(100000/128)
#define B_SC 512               // scatter blocks
#define CHUNK 3125             // 512*3125 = 1600000 exactly
#define CAP 2560               // fixed slots per bucket (mean 2045, +11 sigma)
#define NODE_BLOCKS 6250       // 16 nodes/block (1 node per 16 lanes)

// srcfeat layout: per node, 8 floats interleaved as
// (as0,g0, as1,g1, as2,g2, as3,g3) -> head-pair hp reads ONE float4 at offset 4*hp.

// ---- K0: fold att_src/att_dst/fc_w through lin_w; also zero bcnt/ocnt ----
__global__ __launch_bounds__(256) void prep_kernel(
        const float* __restrict__ lin_w, const float* __restrict__ att_src,
        const float* __restrict__ att_dst, const float* __restrict__ fc_w,
        const float* __restrict__ bias, const float* __restrict__ fc_b,
        float* __restrict__ w_all, float* __restrict__ c0,
        int* __restrict__ bcnt, int* __restrict__ ocnt) {
    __shared__ float red[256];
    int h = blockIdx.x;   // 0..3
    int f = threadIdx.x;  // 0..255
    if (bcnt) {           // zero bucket counters (sorted path only)
        int i = h * 256 + f;
        if (i < W_BUCKETS) bcnt[i] = 0;
        if (i == 0) *ocnt = 0;
    }
    float a0 = 0.f, a1 = 0.f, a2 = 0.f;
    for (int c = 0; c < HIDDEN; ++c) {
        float lw = lin_w[(size_t)(h * HIDDEN + c) * F_IN + f];
        a0 += att_src[h * HIDDEN + c] * lw;
        a1 += att_dst[h * HIDDEN + c] * lw;
        a2 += fc_w[h * HIDDEN + c] * lw;
    }
    w_all[(0 + h) * F_IN + f] = a0;
    w_all[(4 + h) * F_IN + f] = a1;
    w_all[(8 + h) * F_IN + f] = a2;
    if (h == 0) {
        red[f] = bias[f] * fc_w[f];
        __syncthreads();
        for (int s = 128; s; s >>= 1) {
            if (f < s) red[f] += red[f + s];
            __syncthreads();
        }
        if (f == 0) c0[0] = red[0] + fc_b[0];
    }
}

// ---- fused K1: heterogeneous blocks, SCATTER FIRST; 12 KB LDS union ----
// blocks [0, B_SC)         : 2-PASS counting-sort scatter. Pass 1 histograms
//                            dst buckets (chunk becomes L2-resident); after a
//                            per-bucket global range reservation, pass 2
//                            re-reads the chunk from L2 and scatters.
//                            LDS: cur[782] = 3.1 KB only.
// blocks [B_SC, B_SC+6250) : per-node 256x12 matvec, 1 node per 16 lanes,
//                            w_all staged in LDS (12 KB).
// Union is now 12 KB (was 28 KB) -> node-block co-residency ceiling rises
// from 20 to 32 waves/CU; round-6 counters showed node was occupancy/latency
// starved (Occ 37%, VALU 21%, 1.35 TB/s).
__global__ __launch_bounds__(256) void node_scatter_kernel(
        const float* __restrict__ x, const float* __restrict__ w_all,
        float* __restrict__ srcfeat, float* __restrict__ dstfeat,
        const int* __restrict__ ei, int* __restrict__ bcnt,
        int* __restrict__ ocnt, int* __restrict__ sorted,
        int2* __restrict__ obuf) {
    __shared__ alignas(16) int smem[3072];   // 12288 B union
    int t = threadIdx.x;
    int b = blockIdx.x;
    if (b < B_SC) {
        // ---------------- 2-pass scatter ----------------
        int* cur = smem;               // count, then cursor (782 ints)
        for (int i = t; i < W_BUCKETS; i += 256) cur[i] = 0;
        __syncthreads();
        int base = b * CHUNK;
        // pass 1: histogram dst buckets
        for (int i = t; i < CHUNK; i += 256) {
            int d = ei[N_EDGES + base + i];
            atomicAdd(&cur[d >> BSHIFT], 1);
        }
        __syncthreads();
        // reserve a contiguous range per present bucket in its static region
        for (int i = t; i < W_BUCKETS; i += 256) {
            int c = cur[i];
            if (c > 0) cur[i] = i * CAP + atomicAdd(&bcnt[i], c);
        }
        __syncthreads();
        // pass 2: scatter (d re-read hits L2)
        for (int i = t; i < CHUNK; i += 256) {
            int e = base + i;
            int s = ei[e];
            int d = ei[N_EDGES + e];
            int k = d >> BSHIFT;
            int pos = atomicAdd(&cur[k], 1);
            if (pos < (k + 1) * CAP) {
                sorted[pos] = s | ((d & BMASK) << 17);
            } else {                       // bucket overflow (never for this input)
                int oi = atomicAdd(ocnt, 1);
                obuf[oi] = make_int2(s, d);
            }
        }
    } else {
        // -------- node matvec (round-4 body; srcfeat store interleaved) --------
        float4* lw = (float4*)smem;    // full 12 KB
        {
            const float4* wr = (const float4*)w_all;
            lw[t] = wr[t];
            lw[t + 256] = wr[t + 256];
            lw[t + 512] = wr[t + 512];
        }
        __syncthreads();
        int tid  = (b - B_SC) * 256 + t;
        int wave = tid >> 6;
        int lane = t & 63;
        int sub  = lane >> 4;
        int l16  = lane & 15;
        int n = wave * 4 + sub;
        if (n >= N_NODES) return;
        const float4* xr = (const float4*)x + (size_t)n * 64;
        float p[12];
#pragma unroll
        for (int r = 0; r < 12; ++r) p[r] = 0.f;
#pragma unroll
        for (int k = 0; k < 4; ++k) {
            float4 xv = xr[l16 + 16 * k];
#pragma unroll
            for (int r = 0; r < 12; ++r) {
                float4 wv = lw[r * 64 + l16 + 16 * k];
                p[r] += xv.x * wv.x + xv.y * wv.y + xv.z * wv.z + xv.w * wv.w;
            }
        }
#pragma unroll
        for (int r = 0; r < 12; ++r) {
            float v = p[r];
            v += __shfl_xor(v, 1);
            v += __shfl_xor(v, 2);
            v += __shfl_xor(v, 4);
            v += __shfl_xor(v, 8);
            p[r] = v;
        }
        if (l16 == 0) {
            // interleaved (as_h, g_h) pairs
            float4* sf = (float4*)(srcfeat + (size_t)n * 8);
            sf[0] = make_float4(p[0], p[8],  p[1], p[9]);
            sf[1] = make_float4(p[2], p[10], p[3], p[11]);
            *(float4*)(dstfeat + (size_t)n * 4) = make_float4(p[4], p[5], p[6], p[7]);
        }
    }
}

// ---- agg4d: per-bucket in-LDS fine sort + 256-thread, head-pair gather ----
// thread t handles node t&127, head-pair t>>7 (round-4 agg4b structure,
// known 33 us), but with interleaved srcfeat each edge costs ONE float4
// load instead of two float2s. Per-head accumulation order unchanged.
__global__ __launch_bounds__(256) void agg4d_kernel(
        const int* __restrict__ sorted, const int* __restrict__ bcnt,
        const float* __restrict__ srcfeat, const float* __restrict__ dstfeat,
        const float* __restrict__ c0, float* __restrict__ out,
        const int* __restrict__ ocnt, const int2* __restrict__ obuf) {
    __shared__ int eds[CAP];
    __shared__ int srt[CAP];
    __shared__ int cnt[128];   // hist, then cursor
    __shared__ int bnd[129];   // exclusive bounds
    __shared__ float red[256];
    __shared__ int s_oc;
    int t = threadIdx.x, k = blockIdx.x;
    if (t == 0) s_oc = *ocnt;
    int begin = k * CAP;
    int len = bcnt[k];
    int lcap = len < CAP ? len : CAP;
    if (t < 128) cnt[t] = 0;
    __syncthreads();
    for (int i = t; i < lcap; i += 256) {
        int p = sorted[begin + i];
        eds[i] = p;
        atomicAdd(&cnt[p >> 17], 1);
    }
    __syncthreads();
    if (t < 128) bnd[t + 1] = cnt[t];
    __syncthreads();
    for (int off = 1; off < 128; off <<= 1) {
        int v = 0;
        if (t < 128 && t >= off) v = bnd[t + 1 - off];
        __syncthreads();
        if (t < 128) bnd[t + 1] += v;
        __syncthreads();
    }
    if (t == 0) bnd[0] = 0;
    if (t < 128) cnt[t] = (t == 0) ? 0 : bnd[t];
    __syncthreads();
    for (int i = t; i < lcap; i += 256) {
        int p = eds[i];
        int pos = atomicAdd(&cnt[p >> 17], 1);
        srt[pos] = p & 0x1FFFF;
    }
    __syncthreads();
    {
        int node = t & 127;        // node within bucket
        int half = t >> 7;         // head pair: 0 -> heads 0,1 ; 1 -> heads 2,3
        int n0 = k * 128 + node;
        float r = 0.f;
        if (n0 < N_NODES) {
            float2 ad = *(const float2*)(dstfeat + (size_t)n0 * 4 + half * 2);
            float de0 = 0.f, de1 = 0.f, nu0 = 0.f, nu1 = 0.f;
            int b0 = bnd[node], e0 = bnd[node + 1];
            int i = b0;
            for (; i + 2 <= e0; i += 2) {
                int sA = srt[i], sB = srt[i + 1];
                float4 vA = *(const float4*)(srcfeat + (size_t)sA * 8 + half * 4);
                float4 vB = *(const float4*)(srcfeat + (size_t)sB * 8 + half * 4);
                float s0A = vA.x + ad.x, s1A = vA.z + ad.y;
                float s0B = vB.x + ad.x, s1B = vB.z + ad.y;
                float x0A = __expf(s0A > 0.f ? s0A : NEG_SLOPE * s0A);
                float x1A = __expf(s1A > 0.f ? s1A : NEG_SLOPE * s1A);
                float x0B = __expf(s0B > 0.f ? s0B : NEG_SLOPE * s0B);
                float x1B = __expf(s1B > 0.f ? s1B : NEG_SLOPE * s1B);
                de0 += x0A; de0 += x0B;
                de1 += x1A; de1 += x1B;
                nu0 += x0A * vA.y; nu0 += x0B * vB.y;
                nu1 += x1A * vA.w; nu1 += x1B * vB.w;
            }
            if (i < e0) {
                int s = srt[i];
                float4 v = *(const float4*)(srcfeat + (size_t)s * 8 + half * 4);
                float s0 = v.x + ad.x, s1 = v.z + ad.y;
                float x0 = __expf(s0 > 0.f ? s0 : NEG_SLOPE * s0);
                float x1 = __expf(s1 > 0.f ? s1 : NEG_SLOPE * s1);
                de0 += x0; de1 += x1;
                nu0 += x0 * v.y; nu1 += x1 * v.w;
            }
            // overflow edges (empty in practice)
            for (int j = 0; j < s_oc; ++j) {
                int2 e = obuf[j];
                if ((e.y >> BSHIFT) == k && (e.y & BMASK) == node) {
                    float4 v = *(const float4*)(srcfeat + (size_t)e.x * 8 + half * 4);
                    float s0 = v.x + ad.x, s1 = v.z + ad.y;
                    float x0 = __expf(s0 > 0.f ? s0 : NEG_SLOPE * s0);
                    float x1 = __expf(s1 > 0.f ? s1 : NEG_SLOPE * s1);
                    de0 += x0; de1 += x1;
                    nu0 += x0 * v.y; nu1 += x1 * v.w;
                }
            }
            r = nu0 / (de0 + 1e-16f) + nu1 / (de1 + 1e-16f);
        }
        red[t] = r;
        __syncthreads();
        if (t < 128) {
            int n = k * 128 + t;
            if (n < N_NODES) out[n] = c0[0] + red[t] + red[t + 128];
        }
    }
}

// =================== fallback atomic path (tiny ws) ===================

__global__ __launch_bounds__(256) void node_only_kernel(
        const float* __restrict__ x, const float* __restrict__ w_all,
        float* __restrict__ srcfeat, float* __restrict__ dstfeat) {
    __shared__ float4 lw[768];
    int t = threadIdx.x;
    {
        const float4* wr = (const float4*)w_all;
        lw[t] = wr[t];
        lw[t + 256] = wr[t + 256];
        lw[t + 512] = wr[t + 512];
    }
    __syncthreads();
    int tid  = blockIdx.x * 256 + t;
    int wave = tid >> 6;
    int lane = t & 63;
    int sub  = lane >> 4;
    int l16  = lane & 15;
    int n = wave * 4 + sub;
    if (n >= N_NODES) return;
    const float4* xr = (const float4*)x + (size_t)n * 64;
    float p[12];
#pragma unroll
    for (int r = 0; r < 12; ++r) p[r] = 0.f;
#pragma unroll
    for (int k = 0; k < 4; ++k) {
        float4 xv = xr[l16 + 16 * k];
#pragma unroll
        for (int r = 0; r < 12; ++r) {
            float4 wv = lw[r * 64 + l16 + 16 * k];
            p[r] += xv.x * wv.x + xv.y * wv.y + xv.z * wv.z + xv.w * wv.w;
        }
    }
#pragma unroll
    for (int r = 0; r < 12; ++r) {
        float v = p[r];
        v += __shfl_xor(v, 1);
        v += __shfl_xor(v, 2);
        v += __shfl_xor(v, 4);
        v += __shfl_xor(v, 8);
        p[r] = v;
    }
    if (l16 == 0) {
        float4* sf = (float4*)(srcfeat + (size_t)n * 8);
        sf[0] = make_float4(p[0], p[8],  p[1], p[9]);
        sf[1] = make_float4(p[2], p[10], p[3], p[11]);
        *(float4*)(dstfeat + (size_t)n * 4) = make_float4(p[4], p[5], p[6], p[7]);
    }
}

__global__ __launch_bounds__(256) void init_nd_kernel(
        float* __restrict__ num, float* __restrict__ den) {
    int i = blockIdx.x * 256 + threadIdx.x;
    if (i < N_NODES * 4) { num[i] = 0.f; den[i] = 0.f; }
}

__global__ __launch_bounds__(256) void edge_acc2_kernel(
        const int* __restrict__ ei, const float* __restrict__ srcfeat,
        const float* __restrict__ dstfeat, float* __restrict__ num,
        float* __restrict__ den) {
    int e = blockIdx.x * 256 + threadIdx.x;
    if (e >= N_EDGES) return;
    int s = ei[e];
    int d = ei[N_EDGES + e];
    const float4* sp = (const float4*)(srcfeat + (size_t)s * 8);
    float4 q0 = sp[0];   // (as0,g0, as1,g1)
    float4 q1 = sp[1];   // (as2,g2, as3,g3)
    float4 ad = *(const float4*)(dstfeat + (size_t)d * 4);
    float sc[4] = {q0.x + ad.x, q0.z + ad.y, q1.x + ad.z, q1.z + ad.w};
    float gg[4] = {q0.y, q0.w, q1.y, q1.w};
    float* np = num + (size_t)d * 4;
    float* dp = den + (size_t)d * 4;
#pragma unroll
    for (int h = 0; h < 4; ++h) {
        float v = sc[h] > 0.f ? sc[h] : NEG_SLOPE * sc[h];
        float ex = __expf(v);
        atomicAdd(dp + h, ex);
        atomicAdd(np + h, ex * gg[h]);
    }
}

__global__ __launch_bounds__(256) void finalize_kernel(
        const float* __restrict__ num, const float* __restrict__ den,
        const float* __restrict__ c0, float* __restrict__ out) {
    int n = blockIdx.x * 256 + threadIdx.x;
    if (n >= N_NODES) return;
    float4 nu = *(const float4*)(num + (size_t)n * 4);
    float4 de = *(const float4*)(den + (size_t)n * 4);
    out[n] = c0[0]
           + nu.x / (de.x + 1e-16f)
           + nu.y / (de.y + 1e-16f)
           + nu.z / (de.z + 1e-16f)
           + nu.w / (de.w + 1e-16f);
}

extern "C" void kernel_launch(void* const* d_in, const int* in_sizes, int n_in,
                              void* d_out, int out_size, void* d_ws, size_t ws_size,
                              hipStream_t stream) {
    const float* x       = (const float*)d_in[0];
    const int*   ei      = (const int*)d_in[1];
    const float* lin_w   = (const float*)d_in[2];
    const float* att_src = (const float*)d_in[3];
    const float* att_dst = (const float*)d_in[4];
    const float* bias    = (const float*)d_in[5];
    const float* fc_w    = (const float*)d_in[6];
    const float* fc_b    = (const float*)d_in[7];
    float* out = (float*)d_out;

    float* ws = (float*)d_ws;
    float* w_all   = ws;            // 3072 (+pad to 4096)
    float* c0      = ws + 3072;
    float* srcfeat = ws + 4096;     // 800000
    float* dstfeat = ws + 804096;   // 400000

    // layout (words from ws base):
    // bcnt   @1204096  (1024 pad) -> 1205120
    // ocnt   @1205120  (64 pad)   -> 1205184
    // obuf   @1205184  (3200000)  -> 4405184   (int2 x N_EDGES, 8B-aligned)
    // sorted @4405184  (2001920)  -> 6407104   (~25.6 MB total)
    const size_t need_words = 6407104;
    if (ws_size >= need_words * 4) {
        int*  bcnt   = (int*)(ws + 1204096);
        int*  ocnt   = (int*)(ws + 1205120);
        int2* obuf   = (int2*)(ws + 1205184);
        int*  sorted = (int*)(ws + 4405184);

        prep_kernel<<<4, 256, 0, stream>>>(lin_w, att_src, att_dst, fc_w, bias,
                                           fc_b, w_all, c0, bcnt, ocnt);
        node_scatter_kernel<<<B_SC + NODE_BLOCKS, 256, 0, stream>>>(
            x, w_all, srcfeat, dstfeat, ei, bcnt, ocnt, sorted, obuf);
        agg4d_kernel<<<W_BUCKETS, 256, 0, stream>>>(
            sorted, bcnt, srcfeat, dstfeat, c0, out, ocnt, obuf);
    } else {
        prep_kernel<<<4, 256, 0, stream>>>(lin_w, att_src, att_dst, fc_w, bias,
                                           fc_b, w_all, c0, (int*)nullptr, (int*)nullptr);
        node_only_kernel<<<(N_NODES + 15) / 16, 256, 0, stream>>>(x, w_all, srcfeat, dstfeat);
        float* num = ws + 1204096;
        float* den = ws + 1604096;
        init_nd_kernel<<<(N_NODES * 4 + 255) / 256, 256, 0, stream>>>(num, den);
        edge_acc2_kernel<<<N_EDGES / 256, 256, 0, stream>>>(ei, srcfeat, dstfeat, num, den);
        finalize_kernel<<<(N_NODES + 255) / 256, 256, 0, stream>>>(num, den, c0, out);
    }
}

// Round 8
// 216.508 us; speedup vs baseline: 1.0523x; 1.0523x over previous
//
#include <hip/hip_runtime.h>
#include <math.h>

#define N_NODES 100000
#define N_EDGES 1600000
#define F_IN 256
#define HIDDEN 64
#define NEG_SLOPE 0.2f

#define BSHIFT 7               // bucket = dst>>7 (128 nodes/bucket)
#define BMASK 127
#define W_BUCKETS 782          // ceil(100000/128)
#define B_SC 512               // scatter blocks
#define CHUNK 3125             // 512*3125 = 1600000 exactly
#define CAP 2560               // fixed slots per bucket (mean 2045, +11 sigma)
#define NODE_BLOCKS 6250       // 16 nodes/block (1 node per 16 lanes)

// srcfeat layout: per node, 8 floats interleaved as
// (as0,g0, as1,g1, as2,g2, as3,g3) -> head-pair hp reads ONE float4 at offset 4*hp.

// ---- K0: fold att_src/att_dst/fc_w through lin_w; also zero bcnt/ocnt ----
__global__ __launch_bounds__(256) void prep_kernel(
        const float* __restrict__ lin_w, const float* __restrict__ att_src,
        const float* __restrict__ att_dst, const float* __restrict__ fc_w,
        const float* __restrict__ bias, const float* __restrict__ fc_b,
        float* __restrict__ w_all, float* __restrict__ c0,
        int* __restrict__ bcnt, int* __restrict__ ocnt) {
    __shared__ float red[256];
    int h = blockIdx.x;   // 0..3
    int f = threadIdx.x;  // 0..255
    if (bcnt) {           // zero bucket counters (sorted path only)
        int i = h * 256 + f;
        if (i < W_BUCKETS) bcnt[i] = 0;
        if (i == 0) *ocnt = 0;
    }
    float a0 = 0.f, a1 = 0.f, a2 = 0.f;
    for (int c = 0; c < HIDDEN; ++c) {
        float lw = lin_w[(size_t)(h * HIDDEN + c) * F_IN + f];
        a0 += att_src[h * HIDDEN + c] * lw;
        a1 += att_dst[h * HIDDEN + c] * lw;
        a2 += fc_w[h * HIDDEN + c] * lw;
    }
    w_all[(0 + h) * F_IN + f] = a0;
    w_all[(4 + h) * F_IN + f] = a1;
    w_all[(8 + h) * F_IN + f] = a2;
    if (h == 0) {
        red[f] = bias[f] * fc_w[f];
        __syncthreads();
        for (int s = 128; s; s >>= 1) {
            if (f < s) red[f] += red[f + s];
            __syncthreads();
        }
        if (f == 0) c0[0] = red[0] + fc_b[0];
    }
}

// ---- fused K1: heterogeneous blocks, SCATTER FIRST (round-4/6 known-good) ----
// blocks [0, B_SC)         : counting-sort scatter, LDS-staged edges + per-
//                            bucket global range reservation (single pass
//                            over ei; 28 KB union). Round-7 showed the 2-pass
//                            L2-re-read variant is strictly worse (write
//                            amplification 29->47 MB) and LDS does not bind
//                            occupancy -- so the 28 KB union is free.
// blocks [B_SC, B_SC+6250) : per-node 256x12 matvec, 1 node per 16 lanes,
//                            w_all staged in LDS (12 KB of the union),
//                            interleaved srcfeat stores.
__global__ __launch_bounds__(256) void node_scatter_kernel(
        const float* __restrict__ x, const float* __restrict__ w_all,
        float* __restrict__ srcfeat, float* __restrict__ dstfeat,
        const int* __restrict__ ei, int* __restrict__ bcnt,
        int* __restrict__ ocnt, int* __restrict__ sorted,
        int2* __restrict__ obuf) {
    __shared__ alignas(16) int smem[2 * CHUNK + W_BUCKETS];  // 28128 B union
    int t = threadIdx.x;
    int b = blockIdx.x;
    if (b < B_SC) {
        // ---------------- scatter (LDS-staged, single pass) ----------------
        int* epk = smem;               // s | (d&127)<<17
        int* ebk = smem + CHUNK;       // bucket id d>>7
        int* cur = smem + 2 * CHUNK;   // count, then cursor
        for (int i = t; i < W_BUCKETS; i += 256) cur[i] = 0;
        __syncthreads();
        int base = b * CHUNK;
        for (int i = t; i < CHUNK; i += 256) {
            int e = base + i;
            int s = ei[e];
            int d = ei[N_EDGES + e];
            epk[i] = s | ((d & BMASK) << 17);
            int k = d >> BSHIFT;
            ebk[i] = k;
            atomicAdd(&cur[k], 1);
        }
        __syncthreads();
        for (int i = t; i < W_BUCKETS; i += 256) {
            int c = cur[i];
            if (c > 0) cur[i] = i * CAP + atomicAdd(&bcnt[i], c);
        }
        __syncthreads();
        for (int i = t; i < CHUNK; i += 256) {
            int k = ebk[i];
            int pos = atomicAdd(&cur[k], 1);
            if (pos < (k + 1) * CAP) {
                sorted[pos] = epk[i];
            } else {                       // bucket overflow (never for this input)
                int oi = atomicAdd(ocnt, 1);
                int p = epk[i];
                obuf[oi] = make_int2(p & 0x1FFFF, (k << BSHIFT) | (p >> 17));
            }
        }
    } else {
        // -------- node matvec (round-4 body; srcfeat store interleaved) --------
        float4* lw = (float4*)smem;    // 12 KB of the union
        {
            const float4* wr = (const float4*)w_all;
            lw[t] = wr[t];
            lw[t + 256] = wr[t + 256];
            lw[t + 512] = wr[t + 512];
        }
        __syncthreads();
        int tid  = (b - B_SC) * 256 + t;
        int wave = tid >> 6;
        int lane = t & 63;
        int sub  = lane >> 4;
        int l16  = lane & 15;
        int n = wave * 4 + sub;
        if (n >= N_NODES) return;
        const float4* xr = (const float4*)x + (size_t)n * 64;
        float p[12];
#pragma unroll
        for (int r = 0; r < 12; ++r) p[r] = 0.f;
#pragma unroll
        for (int k = 0; k < 4; ++k) {
            float4 xv = xr[l16 + 16 * k];
#pragma unroll
            for (int r = 0; r < 12; ++r) {
                float4 wv = lw[r * 64 + l16 + 16 * k];
                p[r] += xv.x * wv.x + xv.y * wv.y + xv.z * wv.z + xv.w * wv.w;
            }
        }
#pragma unroll
        for (int r = 0; r < 12; ++r) {
            float v = p[r];
            v += __shfl_xor(v, 1);
            v += __shfl_xor(v, 2);
            v += __shfl_xor(v, 4);
            v += __shfl_xor(v, 8);
            p[r] = v;
        }
        if (l16 == 0) {
            // interleaved (as_h, g_h) pairs
            float4* sf = (float4*)(srcfeat + (size_t)n * 8);
            sf[0] = make_float4(p[0], p[8],  p[1], p[9]);
            sf[1] = make_float4(p[2], p[10], p[3], p[11]);
            *(float4*)(dstfeat + (size_t)n * 4) = make_float4(p[4], p[5], p[6], p[7]);
        }
    }
}

// ---- agg4d: per-bucket in-LDS fine sort + 256-thread, head-pair gather ----
// thread t handles node t&127, head-pair t>>7 (round-4 agg4b structure),
// with interleaved srcfeat each edge costs ONE float4 load instead of two
// float2s. Per-head accumulation order unchanged.
__global__ __launch_bounds__(256) void agg4d_kernel(
        const int* __restrict__ sorted, const int* __restrict__ bcnt,
        const float* __restrict__ srcfeat, const float* __restrict__ dstfeat,
        const float* __restrict__ c0, float* __restrict__ out,
        const int* __restrict__ ocnt, const int2* __restrict__ obuf) {
    __shared__ int eds[CAP];
    __shared__ int srt[CAP];
    __shared__ int cnt[128];   // hist, then cursor
    __shared__ int bnd[129];   // exclusive bounds
    __shared__ float red[256];
    __shared__ int s_oc;
    int t = threadIdx.x, k = blockIdx.x;
    if (t == 0) s_oc = *ocnt;
    int begin = k * CAP;
    int len = bcnt[k];
    int lcap = len < CAP ? len : CAP;
    if (t < 128) cnt[t] = 0;
    __syncthreads();
    for (int i = t; i < lcap; i += 256) {
        int p = sorted[begin + i];
        eds[i] = p;
        atomicAdd(&cnt[p >> 17], 1);
    }
    __syncthreads();
    if (t < 128) bnd[t + 1] = cnt[t];
    __syncthreads();
    for (int off = 1; off < 128; off <<= 1) {
        int v = 0;
        if (t < 128 && t >= off) v = bnd[t + 1 - off];
        __syncthreads();
        if (t < 128) bnd[t + 1] += v;
        __syncthreads();
    }
    if (t == 0) bnd[0] = 0;
    if (t < 128) cnt[t] = (t == 0) ? 0 : bnd[t];
    __syncthreads();
    for (int i = t; i < lcap; i += 256) {
        int p = eds[i];
        int pos = atomicAdd(&cnt[p >> 17], 1);
        srt[pos] = p & 0x1FFFF;
    }
    __syncthreads();
    {
        int node = t & 127;        // node within bucket
        int half = t >> 7;         // head pair: 0 -> heads 0,1 ; 1 -> heads 2,3
        int n0 = k * 128 + node;
        float r = 0.f;
        if (n0 < N_NODES) {
            float2 ad = *(const float2*)(dstfeat + (size_t)n0 * 4 + half * 2);
            float de0 = 0.f, de1 = 0.f, nu0 = 0.f, nu1 = 0.f;
            int b0 = bnd[node], e0 = bnd[node + 1];
            int i = b0;
            for (; i + 2 <= e0; i += 2) {
                int sA = srt[i], sB = srt[i + 1];
                float4 vA = *(const float4*)(srcfeat + (size_t)sA * 8 + half * 4);
                float4 vB = *(const float4*)(srcfeat + (size_t)sB * 8 + half * 4);
                float s0A = vA.x + ad.x, s1A = vA.z + ad.y;
                float s0B = vB.x + ad.x, s1B = vB.z + ad.y;
                float x0A = __expf(s0A > 0.f ? s0A : NEG_SLOPE * s0A);
                float x1A = __expf(s1A > 0.f ? s1A : NEG_SLOPE * s1A);
                float x0B = __expf(s0B > 0.f ? s0B : NEG_SLOPE * s0B);
                float x1B = __expf(s1B > 0.f ? s1B : NEG_SLOPE * s1B);
                de0 += x0A; de0 += x0B;
                de1 += x1A; de1 += x1B;
                nu0 += x0A * vA.y; nu0 += x0B * vB.y;
                nu1 += x1A * vA.w; nu1 += x1B * vB.w;
            }
            if (i < e0) {
                int s = srt[i];
                float4 v = *(const float4*)(srcfeat + (size_t)s * 8 + half * 4);
                float s0 = v.x + ad.x, s1 = v.z + ad.y;
                float x0 = __expf(s0 > 0.f ? s0 : NEG_SLOPE * s0);
                float x1 = __expf(s1 > 0.f ? s1 : NEG_SLOPE * s1);
                de0 += x0; de1 += x1;
                nu0 += x0 * v.y; nu1 += x1 * v.w;
            }
            // overflow edges (empty in practice)
            for (int j = 0; j < s_oc; ++j) {
                int2 e = obuf[j];
                if ((e.y >> BSHIFT) == k && (e.y & BMASK) == node) {
                    float4 v = *(const float4*)(srcfeat + (size_t)e.x * 8 + half * 4);
                    float s0 = v.x + ad.x, s1 = v.z + ad.y;
                    float x0 = __expf(s0 > 0.f ? s0 : NEG_SLOPE * s0);
                    float x1 = __expf(s1 > 0.f ? s1 : NEG_SLOPE * s1);
                    de0 += x0; de1 += x1;
                    nu0 += x0 * v.y; nu1 += x1 * v.w;
                }
            }
            r = nu0 / (de0 + 1e-16f) + nu1 / (de1 + 1e-16f);
        }
        red[t] = r;
        __syncthreads();
        if (t < 128) {
            int n = k * 128 + t;
            if (n < N_NODES) out[n] = c0[0] + red[t] + red[t + 128];
        }
    }
}

// =================== fallback atomic path (tiny ws) ===================

__global__ __launch_bounds__(256) void node_only_kernel(
        const float* __restrict__ x, const float* __restrict__ w_all,
        float* __restrict__ srcfeat, float* __restrict__ dstfeat) {
    __shared__ float4 lw[768];
    int t = threadIdx.x;
    {
        const float4* wr = (const float4*)w_all;
        lw[t] = wr[t];
        lw[t + 256] = wr[t + 256];
        lw[t + 512] = wr[t + 512];
    }
    __syncthreads();
    int tid  = blockIdx.x * 256 + t;
    int wave = tid >> 6;
    int lane = t & 63;
    int sub  = lane >> 4;
    int l16  = lane & 15;
    int n = wave * 4 + sub;
    if (n >= N_NODES) return;
    const float4* xr = (const float4*)x + (size_t)n * 64;
    float p[12];
#pragma unroll
    for (int r = 0; r < 12; ++r) p[r] = 0.f;
#pragma unroll
    for (int k = 0; k < 4; ++k) {
        float4 xv = xr[l16 + 16 * k];
#pragma unroll
        for (int r = 0; r < 12; ++r) {
            float4 wv = lw[r * 64 + l16 + 16 * k];
            p[r] += xv.x * wv.x + xv.y * wv.y + xv.z * wv.z + xv.w * wv.w;
        }
    }
#pragma unroll
    for (int r = 0; r < 12; ++r) {
        float v = p[r];
        v += __shfl_xor(v, 1);
        v += __shfl_xor(v, 2);
        v += __shfl_xor(v, 4);
        v += __shfl_xor(v, 8);
        p[r] = v;
    }
    if (l16 == 0) {
        float4* sf = (float4*)(srcfeat + (size_t)n * 8);
        sf[0] = make_float4(p[0], p[8],  p[1], p[9]);
        sf[1] = make_float4(p[2], p[10], p[3], p[11]);
        *(float4*)(dstfeat + (size_t)n * 4) = make_float4(p[4], p[5], p[6], p[7]);
    }
}

__global__ __launch_bounds__(256) void init_nd_kernel(
        float* __restrict__ num, float* __restrict__ den) {
    int i = blockIdx.x * 256 + threadIdx.x;
    if (i < N_NODES * 4) { num[i] = 0.f; den[i] = 0.f; }
}

__global__ __launch_bounds__(256) void edge_acc2_kernel(
        const int* __restrict__ ei, const float* __restrict__ srcfeat,
        const float* __restrict__ dstfeat, float* __restrict__ num,
        float* __restrict__ den) {
    int e = blockIdx.x * 256 + threadIdx.x;
    if (e >= N_EDGES) return;
    int s = ei[e];
    int d = ei[N_EDGES + e];
    const float4* sp = (const float4*)(srcfeat + (size_t)s * 8);
    float4 q0 = sp[0];   // (as0,g0, as1,g1)
    float4 q1 = sp[1];   // (as2,g2, as3,g3)
    float4 ad = *(const float4*)(dstfeat + (size_t)d * 4);
    float sc[4] = {q0.x + ad.x, q0.z + ad.y, q1.x + ad.z, q1.z + ad.w};
    float gg[4] = {q0.y, q0.w, q1.y, q1.w};
    float* np = num + (size_t)d * 4;
    float* dp = den + (size_t)d * 4;
#pragma unroll
    for (int h = 0; h < 4; ++h) {
        float v = sc[h] > 0.f ? sc[h] : NEG_SLOPE * sc[h];
        float ex = __expf(v);
        atomicAdd(dp + h, ex);
        atomicAdd(np + h, ex * gg[h]);
    }
}

__global__ __launch_bounds__(256) void finalize_kernel(
        const float* __restrict__ num, const float* __restrict__ den,
        const float* __restrict__ c0, float* __restrict__ out) {
    int n = blockIdx.x * 256 + threadIdx.x;
    if (n >= N_NODES) return;
    float4 nu = *(const float4*)(num + (size_t)n * 4);
    float4 de = *(const float4*)(den + (size_t)n * 4);
    out[n] = c0[0]
           + nu.x / (de.x + 1e-16f)
           + nu.y / (de.y + 1e-16f)
           + nu.z / (de.z + 1e-16f)
           + nu.w / (de.w + 1e-16f);
}

extern "C" void kernel_launch(void* const* d_in, const int* in_sizes, int n_in,
                              void* d_out, int out_size, void* d_ws, size_t ws_size,
                              hipStream_t stream) {
    const float* x       = (const float*)d_in[0];
    const int*   ei      = (const int*)d_in[1];
    const float* lin_w   = (const float*)d_in[2];
    const float* att_src = (const float*)d_in[3];
    const float* att_dst = (const float*)d_in[4];
    const float* bias    = (const float*)d_in[5];
    const float* fc_w    = (const float*)d_in[6];
    const float* fc_b    = (const float*)d_in[7];
    float* out = (float*)d_out;

    float* ws = (float*)d_ws;
    float* w_all   = ws;            // 3072 (+pad to 4096)
    float* c0      = ws + 3072;
    float* srcfeat = ws + 4096;     // 800000
    float* dstfeat = ws + 804096;   // 400000

    // layout (words from ws base):
    // bcnt   @1204096  (1024 pad) -> 1205120
    // ocnt   @1205120  (64 pad)   -> 1205184
    // obuf   @1205184  (3200000)  -> 4405184   (int2 x N_EDGES, 8B-aligned)
    // sorted @4405184  (2001920)  -> 6407104   (~25.6 MB total)
    const size_t need_words = 6407104;
    if (ws_size >= need_words * 4) {
        int*  bcnt   = (int*)(ws + 1204096);
        int*  ocnt   = (int*)(ws + 1205120);
        int2* obuf   = (int2*)(ws + 1205184);
        int*  sorted = (int*)(ws + 4405184);

        prep_kernel<<<4, 256, 0, stream>>>(lin_w, att_src, att_dst, fc_w, bias,
                                           fc_b, w_all, c0, bcnt, ocnt);
        node_scatter_kernel<<<B_SC + NODE_BLOCKS, 256, 0, stream>>>(
            x, w_all, srcfeat, dstfeat, ei, bcnt, ocnt, sorted, obuf);
        agg4d_kernel<<<W_BUCKETS, 256, 0, stream>>>(
            sorted, bcnt, srcfeat, dstfeat, c0, out, ocnt, obuf);
    } else {
        prep_kernel<<<4, 256, 0, stream>>>(lin_w, att_src, att_dst, fc_w, bias,
                                           fc_b, w_all, c0, (int*)nullptr, (int*)nullptr);
        node_only_kernel<<<(N_NODES + 15) / 16, 256, 0, stream>>>(x, w_all, srcfeat, dstfeat);
        float* num = ws + 1204096;
        float* den = ws + 1604096;
        init_nd_kernel<<<(N_NODES * 4 + 255) / 256, 256, 0, stream>>>(num, den);
        edge_acc2_kernel<<<N_EDGES / 256, 256, 0, stream>>>(ei, srcfeat, dstfeat, num, den);
        finalize_kernel<<<(N_NODES + 255) / 256, 256, 0, stream>>>(num, den, c0, out);
    }
}